// Round 1
// baseline (1581.397 us; speedup 1.0000x reference)
//
#include <hip/hip_runtime.h>

#define B_ROWS  16384
#define IN_DIM  1024
#define NEXP    8
#define HID     128
#define NCLS    1024

// ---------------------------------------------------------------------------
// Kernel 1: gating. One wave (64 lanes) per row. Computes logits = x@gate_w+gb,
// softmax over 8 experts, top-2 (value-desc, first-index tie-break like
// jax.lax.top_k), writes (idx0,idx1) and (val0,val1) per row to workspace.
// ---------------------------------------------------------------------------
__global__ __launch_bounds__(256) void gate_kernel(
    const float* __restrict__ x, const float* __restrict__ gw,
    const float* __restrict__ gb, int2* __restrict__ tidx,
    float2* __restrict__ tval) {
  const int wave = threadIdx.x >> 6;
  const int lane = threadIdx.x & 63;
  const int row  = blockIdx.x * 4 + wave;
  if (row >= B_ROWS) return;

  const float* xr = x + (size_t)row * IN_DIM;
  float acc[NEXP];
#pragma unroll
  for (int e = 0; e < NEXP; ++e) acc[e] = 0.f;

  for (int j = lane; j < IN_DIM; j += 64) {
    const float xv = xr[j];
#pragma unroll
    for (int e = 0; e < NEXP; ++e)
      acc[e] = fmaf(xv, gw[j * NEXP + e], acc[e]);
  }

  // wave-wide butterfly reduce (64 lanes)
#pragma unroll
  for (int e = 0; e < NEXP; ++e) {
#pragma unroll
    for (int off = 32; off > 0; off >>= 1)
      acc[e] += __shfl_xor(acc[e], off);
  }

  if (lane == 0) {
    float l[NEXP];
#pragma unroll
    for (int e = 0; e < NEXP; ++e) l[e] = acc[e] + gb[e];
    float m = l[0];
#pragma unroll
    for (int e = 1; e < NEXP; ++e) m = fmaxf(m, l[e]);
    float p[NEXP], s = 0.f;
#pragma unroll
    for (int e = 0; e < NEXP; ++e) { p[e] = __expf(l[e] - m); s += p[e]; }
    const float inv = 1.f / s;
    int   i0 = 0;  float v0 = p[0];
#pragma unroll
    for (int e = 1; e < NEXP; ++e) if (p[e] > v0) { v0 = p[e]; i0 = e; }
    int   i1 = -1; float v1 = -1.f;
#pragma unroll
    for (int e = 0; e < NEXP; ++e)
      if (e != i0 && p[e] > v1) { v1 = p[e]; i1 = e; }
    tidx[row] = make_int2(i0, i1);
    tval[row] = make_float2(v0 * inv, v1 * inv);
  }
}

// ---------------------------------------------------------------------------
// Kernel 2: expert compute. One block (256 thr) per row. x row staged in LDS.
// Threads 0..127 compute h for expert slot 0, threads 128..255 for slot 1.
// Then all 256 threads produce the 1024 output columns (4 each), combining
// both slots. No atomics: each row's output written exactly once.
// ---------------------------------------------------------------------------
__global__ __launch_bounds__(256) void expert_kernel(
    const float* __restrict__ x,  const float* __restrict__ w1,
    const float* __restrict__ b1, const float* __restrict__ w2,
    const float* __restrict__ b2, const int2* __restrict__ tidx,
    const float2* __restrict__ tval, float* __restrict__ out) {
  const int row = blockIdx.x;
  const int t   = threadIdx.x;

  __shared__ float xs[IN_DIM];
  __shared__ float hs[2][HID];

  // coalesced float4 row load: 256 threads * 16B = 4KB
  {
    const float4* xr4 = (const float4*)(x + (size_t)row * IN_DIM);
    ((float4*)xs)[t] = xr4[t];
  }
  __syncthreads();

  const int2   idx = tidx[row];
  const float2 val = tval[row];

  // phase A: h[slot][hc] = relu(x . w1[e][:,hc] + b1[e][hc])
  {
    const int slot = t >> 7;          // 0 or 1
    const int hc   = t & 127;
    const int e    = slot ? idx.y : idx.x;
    const float* W1 = w1 + (size_t)e * IN_DIM * HID;
    float acc = b1[e * HID + hc];
#pragma unroll 8
    for (int i = 0; i < IN_DIM; ++i)
      acc = fmaf(xs[i], W1[(size_t)i * HID + hc], acc);
    hs[slot][hc] = fmaxf(acc, 0.f);
  }
  __syncthreads();

  // phase B: out[row][c] = v0*(h0.w2[e0][:,c] + b2[e0][c]) + v1*(...)
  const float* W2a = w2 + (size_t)idx.x * HID * NCLS;
  const float* W2b = w2 + (size_t)idx.y * HID * NCLS;
  const float  v0 = val.x, v1 = val.y;
#pragma unroll
  for (int cc = 0; cc < NCLS / 256; ++cc) {
    const int c = cc * 256 + t;
    float a0 = b2[idx.x * NCLS + c];
    float a1 = b2[idx.y * NCLS + c];
#pragma unroll 8
    for (int h = 0; h < HID; ++h) {
      a0 = fmaf(hs[0][h], W2a[(size_t)h * NCLS + c], a0);
      a1 = fmaf(hs[1][h], W2b[(size_t)h * NCLS + c], a1);
    }
    out[(size_t)row * NCLS + c] = fmaf(v0, a0, v1 * a1);
  }
}

// ---------------------------------------------------------------------------
// Kernel 3: gates_sum output. Single block reduces top_vals over the batch,
// broadcasts the two scalars across 1024 columns each.
// ---------------------------------------------------------------------------
__global__ __launch_bounds__(256) void gates_out_kernel(
    const float2* __restrict__ tval, float* __restrict__ out) {
  __shared__ float r0[256], r1[256];
  float s0 = 0.f, s1 = 0.f;
  for (int i = threadIdx.x; i < B_ROWS; i += 256) {
    const float2 v = tval[i];
    s0 += v.x; s1 += v.y;
  }
  r0[threadIdx.x] = s0; r1[threadIdx.x] = s1;
  __syncthreads();
#pragma unroll
  for (int s = 128; s > 0; s >>= 1) {
    if (threadIdx.x < s) {
      r0[threadIdx.x] += r0[threadIdx.x + s];
      r1[threadIdx.x] += r1[threadIdx.x + s];
    }
    __syncthreads();
  }
  const float g0 = r0[0], g1 = r1[0];
  float* gout = out + (size_t)B_ROWS * NCLS;
  for (int c = threadIdx.x; c < NCLS; c += 256) {
    gout[c]        = g0;
    gout[NCLS + c] = g1;
  }
}

extern "C" void kernel_launch(void* const* d_in, const int* in_sizes, int n_in,
                              void* d_out, int out_size, void* d_ws, size_t ws_size,
                              hipStream_t stream) {
  const float* x   = (const float*)d_in[0];
  const float* gw  = (const float*)d_in[1];
  const float* gb  = (const float*)d_in[2];
  const float* w1  = (const float*)d_in[3];
  const float* b1  = (const float*)d_in[4];
  const float* w2  = (const float*)d_in[5];
  const float* b2  = (const float*)d_in[6];
  float* out = (float*)d_out;

  // workspace: [tidx: 16384*int2][tval: 16384*float2]
  int2*   tidx = (int2*)d_ws;
  float2* tval = (float2*)((char*)d_ws + (size_t)B_ROWS * sizeof(int2));

  gate_kernel<<<B_ROWS / 4, 256, 0, stream>>>(x, gw, gb, tidx, tval);
  expert_kernel<<<B_ROWS, 256, 0, stream>>>(x, w1, b1, w2, b2, tidx, tval, out);
  gates_out_kernel<<<1, 256, 0, stream>>>(tval, out);
}

// Round 2
// 545.471 us; speedup vs baseline: 2.8991x; 2.8991x over previous
//
#include <hip/hip_runtime.h>

#define B_ROWS  16384
#define IN_DIM  1024
#define NEXP    8
#define HID     128
#define NCLS    1024

typedef __attribute__((ext_vector_type(8))) short bf16x8;
typedef __attribute__((ext_vector_type(4))) float f32x4;
typedef __attribute__((ext_vector_type(4))) unsigned int u32x4;
typedef __attribute__((ext_vector_type(8))) unsigned short u16x8;

__device__ __forceinline__ unsigned short f2bf(float f) {
  union { float f; unsigned u; } v; v.f = f;
  unsigned r = v.u + 0x7FFFu + ((v.u >> 16) & 1u);
  return (unsigned short)(r >> 16);
}

// ---------------------------------------------------------------------------
// Transpose + fp32->bf16 convert: in [E][R][C] fp32 -> out [E][C][R] bf16.
// ---------------------------------------------------------------------------
__global__ __launch_bounds__(256) void transpose_cvt_kernel(
    const float* __restrict__ in, unsigned short* __restrict__ out,
    int R, int C) {
  __shared__ float tile[32][33];
  const int e = blockIdx.z;
  in  += (size_t)e * R * C;
  out += (size_t)e * R * C;
  const int c0 = blockIdx.x * 32, r0 = blockIdx.y * 32;
  const int tx = threadIdx.x, ty = threadIdx.y;
#pragma unroll
  for (int i = ty; i < 32; i += 8)
    tile[i][tx] = in[(size_t)(r0 + i) * C + c0 + tx];
  __syncthreads();
#pragma unroll
  for (int i = ty; i < 32; i += 8)
    out[(size_t)(c0 + i) * R + r0 + tx] = f2bf(tile[tx][i]);
}

// ---------------------------------------------------------------------------
// Gating: one wave per row. softmax -> top-2 -> scatter row into pair bin.
// ---------------------------------------------------------------------------
__global__ __launch_bounds__(256) void gate_kernel(
    const float* __restrict__ x, const float* __restrict__ gw,
    const float* __restrict__ gb, float2* __restrict__ tval,
    int* __restrict__ rowlist, int* __restrict__ cursors) {
  const int wave = threadIdx.x >> 6;
  const int lane = threadIdx.x & 63;
  const int row  = blockIdx.x * 4 + wave;
  if (row >= B_ROWS) return;

  const float* xr = x + (size_t)row * IN_DIM;
  float acc[NEXP];
#pragma unroll
  for (int e = 0; e < NEXP; ++e) acc[e] = 0.f;

  for (int j = lane; j < IN_DIM; j += 64) {
    const float xv = xr[j];
#pragma unroll
    for (int e = 0; e < NEXP; ++e)
      acc[e] = fmaf(xv, gw[j * NEXP + e], acc[e]);
  }
#pragma unroll
  for (int e = 0; e < NEXP; ++e) {
#pragma unroll
    for (int off = 32; off > 0; off >>= 1)
      acc[e] += __shfl_xor(acc[e], off);
  }

  if (lane == 0) {
    float l[NEXP];
#pragma unroll
    for (int e = 0; e < NEXP; ++e) l[e] = acc[e] + gb[e];
    float m = l[0];
#pragma unroll
    for (int e = 1; e < NEXP; ++e) m = fmaxf(m, l[e]);
    float p[NEXP], s = 0.f;
#pragma unroll
    for (int e = 0; e < NEXP; ++e) { p[e] = __expf(l[e] - m); s += p[e]; }
    const float inv = 1.f / s;
    int   i0 = 0;  float v0 = p[0];
#pragma unroll
    for (int e = 1; e < NEXP; ++e) if (p[e] > v0) { v0 = p[e]; i0 = e; }
    int   i1 = -1; float v1 = -1.f;
#pragma unroll
    for (int e = 0; e < NEXP; ++e)
      if (e != i0 && p[e] > v1) { v1 = p[e]; i1 = e; }
    tval[row] = make_float2(v0 * inv, v1 * inv);
    const int pair = i0 * NEXP + i1;
    const int pos  = atomicAdd(&cursors[pair], 1);
    rowlist[(size_t)pair * B_ROWS + pos] = row;
  }
}

// ---------------------------------------------------------------------------
// Pair GEMM: one block = 64 rows sharing the same (e0,e1) expert pair.
// GEMM1: H = relu(Xg@W1 + b1) * gateval (both experts, shared Xg staging)
// GEMM2: out = H_a@W2_a + H_b@W2_b + v0*b2_a + v1*b2_b   (written once)
// bf16 MFMA 16x16x32, fp32 accumulate. 4 waves (2x2).
// ---------------------------------------------------------------------------
__global__ __launch_bounds__(256) void moe_pair_gemm(
    const float* __restrict__ x, const unsigned short* __restrict__ w1bt,
    const float* __restrict__ b1, const unsigned short* __restrict__ w2bt,
    const float* __restrict__ b2, const int* __restrict__ rowlist,
    const float2* __restrict__ tval, const int* __restrict__ cursors,
    float* __restrict__ out) {
  const int p     = blockIdx.y;
  const int cnt   = cursors[p];
  const int start = blockIdx.x * 64;
  if (start >= cnt) return;
  const int nr = min(64, cnt - start);
  const int ea = p >> 3, eb = p & 7;

  // LDS layout (61184 B): [As|Bsa|Bsb] union [W2as|W2bs] ; HsA ; HsB ; rowl ; vals
  __shared__ __attribute__((aligned(16))) unsigned char smem[61184];
  unsigned short* As   = (unsigned short*)(smem);            // [64][40]
  unsigned short* Bsa  = (unsigned short*)(smem + 5120);     // [128][40]
  unsigned short* Bsb  = (unsigned short*)(smem + 15360);    // [128][40]
  unsigned short* W2as = (unsigned short*)(smem);            // [32][136]
  unsigned short* W2bs = (unsigned short*)(smem + 8704);     // [32][136]
  unsigned short* HsA  = (unsigned short*)(smem + 25600);    // [64][136]
  unsigned short* HsB  = (unsigned short*)(smem + 43008);    // [64][136]
  int*    rowl = (int*)(smem + 60416);
  float2* vals = (float2*)(smem + 60672);

  const int t = threadIdx.x;
  if (t < 64) {
    const int rr = rowlist[(size_t)p * B_ROWS + start + ((t < nr) ? t : 0)];
    rowl[t] = rr;
    vals[t] = tval[rr];
  }
  __syncthreads();

  const int wid = t >> 6, l = t & 63;
  const int wr = wid >> 1, wc = wid & 1;
  const int lg = l >> 4,   ln = l & 15;

  f32x4 accA[2][4] = {{{0.f}}};
  f32x4 accB[2][4] = {{{0.f}}};

  // ------------------------- GEMM1: K=1024, BK=32 -------------------------
  const int r_s = t >> 2, c_s = t & 3;   // As staging: row, 8-float chunk
  const int n_s = t >> 1, h_s = t & 1;   // Bs staging: n-row, 16-elem half
  const float* xrow = x + (size_t)rowl[r_s] * IN_DIM + c_s * 8;
  const size_t boa = ((size_t)ea * HID + n_s) * IN_DIM + h_s * 16;
  const size_t bob = ((size_t)eb * HID + n_s) * IN_DIM + h_s * 16;

  for (int kk = 0; kk < 32; ++kk) {
    const int k0 = kk * 32;
    {
      const float4 f0 = *(const float4*)(xrow + k0);
      const float4 f1 = *(const float4*)(xrow + k0 + 4);
      u16x8 u;
      u[0]=f2bf(f0.x); u[1]=f2bf(f0.y); u[2]=f2bf(f0.z); u[3]=f2bf(f0.w);
      u[4]=f2bf(f1.x); u[5]=f2bf(f1.y); u[6]=f2bf(f1.z); u[7]=f2bf(f1.w);
      *(u16x8*)&As[r_s * 40 + c_s * 8] = u;
    }
    {
      const u32x4* pa = (const u32x4*)(w1bt + boa + k0);
      *(u32x4*)&Bsa[n_s * 40 + h_s * 16]     = pa[0];
      *(u32x4*)&Bsa[n_s * 40 + h_s * 16 + 8] = pa[1];
      const u32x4* pb = (const u32x4*)(w1bt + bob + k0);
      *(u32x4*)&Bsb[n_s * 40 + h_s * 16]     = pb[0];
      *(u32x4*)&Bsb[n_s * 40 + h_s * 16 + 8] = pb[1];
    }
    __syncthreads();
    bf16x8 af[2], bfa[4], bfb[4];
#pragma unroll
    for (int ms = 0; ms < 2; ++ms)
      af[ms] = *(const bf16x8*)&As[(wr*32 + ms*16 + ln) * 40 + lg*8];
#pragma unroll
    for (int ns = 0; ns < 4; ++ns) {
      bfa[ns] = *(const bf16x8*)&Bsa[(wc*64 + ns*16 + ln) * 40 + lg*8];
      bfb[ns] = *(const bf16x8*)&Bsb[(wc*64 + ns*16 + ln) * 40 + lg*8];
    }
#pragma unroll
    for (int ms = 0; ms < 2; ++ms)
#pragma unroll
      for (int ns = 0; ns < 4; ++ns) {
        accA[ms][ns] = __builtin_amdgcn_mfma_f32_16x16x32_bf16(af[ms], bfa[ns], accA[ms][ns], 0, 0, 0);
        accB[ms][ns] = __builtin_amdgcn_mfma_f32_16x16x32_bf16(af[ms], bfb[ns], accB[ms][ns], 0, 0, 0);
      }
    __syncthreads();
  }

  // per-lane row gate values
  float2 vv[2][4];
#pragma unroll
  for (int ms = 0; ms < 2; ++ms)
#pragma unroll
    for (int r = 0; r < 4; ++r)
      vv[ms][r] = vals[wr*32 + ms*16 + lg*4 + r];

  float b1a[4], b1b[4];
#pragma unroll
  for (int ns = 0; ns < 4; ++ns) {
    const int col = wc*64 + ns*16 + ln;
    b1a[ns] = b1[ea * HID + col];
    b1b[ns] = b1[eb * HID + col];
  }

  // epilogue: relu + pre-scale by gate value, bf16 -> Hs
#pragma unroll
  for (int ms = 0; ms < 2; ++ms)
#pragma unroll
    for (int ns = 0; ns < 4; ++ns)
#pragma unroll
      for (int r = 0; r < 4; ++r) {
        const int row = wr*32 + ms*16 + lg*4 + r;
        const int col = wc*64 + ns*16 + ln;
        const float ha = fmaxf(accA[ms][ns][r] + b1a[ns], 0.f) * vv[ms][r].x;
        const float hb = fmaxf(accB[ms][ns][r] + b1b[ns], 0.f) * vv[ms][r].y;
        HsA[row * 136 + col] = f2bf(ha);
        HsB[row * 136 + col] = f2bf(hb);
      }
  __syncthreads();

  // --------------------- GEMM2: 32 chunks of 32 columns --------------------
  const int n2 = t >> 3, q2 = t & 7;   // W2 staging: n-row, 16-elem chunk
  for (int ch = 0; ch < 32; ++ch) {
    {
      const size_t so = ((size_t)ea * NCLS + ch*32 + n2) * HID + q2*16;
      const u32x4* pa = (const u32x4*)(w2bt + so);
      *(u32x4*)&W2as[n2 * 136 + q2*16]     = pa[0];
      *(u32x4*)&W2as[n2 * 136 + q2*16 + 8] = pa[1];
      const size_t sb = ((size_t)eb * NCLS + ch*32 + n2) * HID + q2*16;
      const u32x4* pb = (const u32x4*)(w2bt + sb);
      *(u32x4*)&W2bs[n2 * 136 + q2*16]     = pb[0];
      *(u32x4*)&W2bs[n2 * 136 + q2*16 + 8] = pb[1];
    }
    __syncthreads();
    f32x4 acc2[2] = {{0.f}};
#pragma unroll
    for (int kk2 = 0; kk2 < 4; ++kk2) {
      const bf16x8 wa = *(const bf16x8*)&W2as[(wc*16 + ln) * 136 + kk2*32 + lg*8];
      const bf16x8 wb = *(const bf16x8*)&W2bs[(wc*16 + ln) * 136 + kk2*32 + lg*8];
#pragma unroll
      for (int ms = 0; ms < 2; ++ms) {
        const bf16x8 ha = *(const bf16x8*)&HsA[(wr*32 + ms*16 + ln) * 136 + kk2*32 + lg*8];
        const bf16x8 hb = *(const bf16x8*)&HsB[(wr*32 + ms*16 + ln) * 136 + kk2*32 + lg*8];
        acc2[ms] = __builtin_amdgcn_mfma_f32_16x16x32_bf16(ha, wa, acc2[ms], 0, 0, 0);
        acc2[ms] = __builtin_amdgcn_mfma_f32_16x16x32_bf16(hb, wb, acc2[ms], 0, 0, 0);
      }
    }
    const int   c   = ch*32 + wc*16 + ln;
    const float b2a = b2[ea * NCLS + c];
    const float b2b = b2[eb * NCLS + c];
#pragma unroll
    for (int ms = 0; ms < 2; ++ms)
#pragma unroll
      for (int r = 0; r < 4; ++r) {
        const int row = wr*32 + ms*16 + lg*4 + r;
        if (row < nr)
          out[(size_t)rowl[row] * NCLS + c] =
              acc2[ms][r] + vv[ms][r].x * b2a + vv[ms][r].y * b2b;
      }
    __syncthreads();
  }
}

// ---------------------------------------------------------------------------
// gates_sum output (unchanged from round 1)
// ---------------------------------------------------------------------------
__global__ __launch_bounds__(256) void gates_out_kernel(
    const float2* __restrict__ tval, float* __restrict__ out) {
  __shared__ float r0[256], r1[256];
  float s0 = 0.f, s1 = 0.f;
  for (int i = threadIdx.x; i < B_ROWS; i += 256) {
    const float2 v = tval[i];
    s0 += v.x; s1 += v.y;
  }
  r0[threadIdx.x] = s0; r1[threadIdx.x] = s1;
  __syncthreads();
#pragma unroll
  for (int s = 128; s > 0; s >>= 1) {
    if (threadIdx.x < s) {
      r0[threadIdx.x] += r0[threadIdx.x + s];
      r1[threadIdx.x] += r1[threadIdx.x + s];
    }
    __syncthreads();
  }
  const float g0 = r0[0], g1 = r1[0];
  float* gout = out + (size_t)B_ROWS * NCLS;
  for (int c = threadIdx.x; c < NCLS; c += 256) {
    gout[c]        = g0;
    gout[NCLS + c] = g1;
  }
}

extern "C" void kernel_launch(void* const* d_in, const int* in_sizes, int n_in,
                              void* d_out, int out_size, void* d_ws, size_t ws_size,
                              hipStream_t stream) {
  const float* x   = (const float*)d_in[0];
  const float* gw  = (const float*)d_in[1];
  const float* gb  = (const float*)d_in[2];
  const float* w1  = (const float*)d_in[3];
  const float* b1  = (const float*)d_in[4];
  const float* w2  = (const float*)d_in[5];
  const float* b2  = (const float*)d_in[6];
  float* out = (float*)d_out;

  // ws layout (bytes), all 256-aligned:
  //   cursors:     0 .. 256          (64 ints)
  //   tval:      256 .. 131328       (16384 float2)
  //   rowlist: 131328 .. 4325632     (64 * 16384 ints)
  //   w1bt:   4325632 .. 6422784     ([8][128][1024] bf16)
  //   w2bt:   6422784 .. 8519936     ([8][1024][128] bf16)
  int*            cursors = (int*)d_ws;
  float2*         tval    = (float2*)((char*)d_ws + 256);
  int*            rowlist = (int*)((char*)d_ws + 131328);
  unsigned short* w1bt    = (unsigned short*)((char*)d_ws + 4325632);
  unsigned short* w2bt    = (unsigned short*)((char*)d_ws + 6422784);

  hipMemsetAsync(cursors, 0, 64 * sizeof(int), stream);

  dim3 tb(32, 8);
  transpose_cvt_kernel<<<dim3(HID / 32, IN_DIM / 32, NEXP), tb, 0, stream>>>(
      w1, w1bt, IN_DIM, HID);
  transpose_cvt_kernel<<<dim3(NCLS / 32, HID / 32, NEXP), tb, 0, stream>>>(
      w2, w2bt, HID, NCLS);

  gate_kernel<<<B_ROWS / 4, 256, 0, stream>>>(x, gw, gb, tval, rowlist, cursors);

  moe_pair_gemm<<<dim3(256, 64), 256, 0, stream>>>(
      x, w1bt, b1, w2bt, b2, rowlist, tval, cursors, out);

  gates_out_kernel<<<1, 256, 0, stream>>>(tval, out);
}